// Round 3
// baseline (1125.394 us; speedup 1.0000x reference)
//
#include <hip/hip_runtime.h>
#include <hip/hip_bf16.h>

// ---------------------------------------------------------------------------
// ScaledDotProductAttentionMemory, round 2:
//  - attention phase split into two high-occupancy streaming kernels:
//      exp_kernel:    S=QK^T/8, mask, exp (no max-sub; logits bounded),
//                     rowsum -> inv, unnormalized P out (bf16 ws / fp32 att)
//      pv_norm_kernel: att = P*inv (coalesced rows) + PV MFMA -> Ow
//  - no block barriers, waves independent, ~60-70 VGPR -> 7-8 waves/SIMD
// Outputs: out (8,1024,1024) fp32 ; att (8,16,1024,1064) fp32
// ---------------------------------------------------------------------------

#define B_ 8
#define NQ 1024
#define NK 1024
#define DM 1024
#define H_ 16
#define DK 64
#define NKM 1064   // nk + M
#define NKP 1104   // padded row length for Kh/Vt (>= 1088 strip + slack)

typedef __attribute__((ext_vector_type(8))) short bf16x8;
typedef __attribute__((ext_vector_type(4))) float f32x4;
typedef __attribute__((ext_vector_type(4))) short short4v;

static __device__ __forceinline__ short f2bf(float x) {
    __hip_bfloat16 h = __float2bfloat16(x);
    return __builtin_bit_cast(short, h);
}
static __device__ __forceinline__ float bf2f(short s) {
    unsigned int u = ((unsigned int)(unsigned short)s) << 16;
    return __builtin_bit_cast(float, u);
}

static __device__ __forceinline__ bf16x8 pack8(const float* __restrict__ p) {
    float4 f0 = *(const float4*)p;
    float4 f1 = *(const float4*)(p + 4);
    bf16x8 a;
    a[0] = f2bf(f0.x); a[1] = f2bf(f0.y); a[2] = f2bf(f0.z); a[3] = f2bf(f0.w);
    a[4] = f2bf(f1.x); a[5] = f2bf(f1.y); a[6] = f2bf(f1.z); a[7] = f2bf(f1.w);
    return a;
}

// --- mask dtype probe: bool(1B) vs int32(4B) -------------------------------
__global__ void detect_mask_kernel(const unsigned int* __restrict__ m, int n_dwords,
                                   int* __restrict__ flag) {
    __shared__ int any_big;
    if (threadIdx.x == 0) any_big = 0;
    __syncthreads();
    for (int i = threadIdx.x; i < n_dwords; i += blockDim.x)
        if (m[i] > 1u) any_big = 1;
    __syncthreads();
    if (threadIdx.x == 0) *flag = any_big ? 0 : 1;   // 1 => int32, 0 => bytes
}

// --- W (K x N) fp32 -> WT (N x K) bf16 --------------------------------------
__global__ void transpose_w_kernel(const float* __restrict__ W, short* __restrict__ WT) {
    __shared__ float t[32][33];
    int tx = threadIdx.x & 31, ty = threadIdx.x >> 5;
    int k0 = blockIdx.x * 32, n0 = blockIdx.y * 32;
#pragma unroll
    for (int r = 0; r < 4; r++)
        t[ty + 8 * r][tx] = W[(size_t)(k0 + ty + 8 * r) * DM + n0 + tx];
    __syncthreads();
#pragma unroll
    for (int r = 0; r < 4; r++)
        WT[(size_t)(n0 + ty + 8 * r) * DM + k0 + tx] = f2bf(t[tx][ty + 8 * r]);
}

// --- memory-slot rows of Kh / Vt (rows 1024..1103; zeros past 1063) --------
__global__ void fill_mem_kernel(const float* __restrict__ m_k, const float* __restrict__ m_v,
                                short* __restrict__ Kh, short* __restrict__ Vt) {
    int blk = blockIdx.x;           // 128 bh * 20 row-groups
    int bh = blk / 20, rb = blk % 20;
    int r = rb * 4 + (threadIdx.x >> 6);    // 0..79
    int d = threadIdx.x & 63;
    int h = bh & 15;
    float kv = 0.f, vv = 0.f;
    if (r < 40) {
        kv = 8.0f * m_k[(size_t)(r * H_ + h) * DK + d];               // sqrt(DK)=8
        vv = 6.324555320336759f * m_v[(size_t)(r * H_ + h) * DK + d]; // sqrt(M)
    }
    int kk = 1024 + r;
    Kh[((size_t)bh * NKP + kk) * 64 + d] = f2bf(kv);
    Vt[((size_t)bh * 64 + d) * NKP + kk] = f2bf(vv);
}

// ---------------------------------------------------------------------------
// Tiled GEMM (unchanged from round 1): C[8192x1024] = A @ BT^T + bias.
// ---------------------------------------------------------------------------
template <int MODE>
__global__ __launch_bounds__(256) void gemm_tile_kernel(
    const float* __restrict__ Af, const short* __restrict__ Ab,
    const short* __restrict__ BT, const float* __restrict__ bias,
    float* __restrict__ outF, short* __restrict__ outB) {
    __shared__ short As[2][4096];
    __shared__ short Bs[2][4096];

    const int tid = threadIdx.x;
    const int lane = tid & 63;
    const int wid = tid >> 6;
    int swz = (blockIdx.x & 7) * 64 + (blockIdx.x >> 3);
    const int mt = swz >> 3;
    const int nt = swz & 7;
    const int brow = mt * 128, bcol = nt * 128;
    const int wr = wid >> 1, wc = wid & 1;
    const int l15 = lane & 15, lg = lane >> 4;

    f32x4 acc[4][4];
#pragma unroll
    for (int m = 0; m < 4; m++)
#pragma unroll
        for (int n = 0; n < 4; n++) acc[m][n] = f32x4{0.f, 0.f, 0.f, 0.f};

    auto stage = [&](int buf, int k0) {
#pragma unroll
        for (int i = 0; i < 2; i++) {
            int c = tid + i * 256;
            int row = c >> 2, slot = c & 3;
            int sw = slot ^ (row & 3);
            bf16x8 av;
            if (MODE == 3) {
                av = *(const bf16x8*)(Ab + (size_t)(brow + row) * DM + k0 + slot * 8);
            } else {
                av = pack8(Af + (size_t)(brow + row) * DM + k0 + slot * 8);
            }
            *(bf16x8*)(&As[buf][row * 32 + sw * 8]) = av;
            bf16x8 bv = *(const bf16x8*)(BT + (size_t)(bcol + row) * DM + k0 + slot * 8);
            *(bf16x8*)(&Bs[buf][row * 32 + sw * 8]) = bv;
        }
    };

    stage(0, 0);
    for (int kt = 0; kt < 32; ++kt) {
        __syncthreads();
        if (kt + 1 < 32) stage((kt + 1) & 1, (kt + 1) * 32);
        const short* Ab_ = As[kt & 1];
        const short* Bb_ = Bs[kt & 1];
        bf16x8 a[4], b[4];
#pragma unroll
        for (int m = 0; m < 4; m++) {
            int row = wr * 64 + m * 16 + l15;
            a[m] = *(const bf16x8*)(Ab_ + row * 32 + ((lg ^ (row & 3)) * 8));
        }
#pragma unroll
        for (int n = 0; n < 4; n++) {
            int row = wc * 64 + n * 16 + l15;
            b[n] = *(const bf16x8*)(Bb_ + row * 32 + ((lg ^ (row & 3)) * 8));
        }
#pragma unroll
        for (int m = 0; m < 4; m++)
#pragma unroll
            for (int n = 0; n < 4; n++)
                acc[m][n] = __builtin_amdgcn_mfma_f32_16x16x32_bf16(a[m], b[n], acc[m][n], 0, 0, 0);
    }

#pragma unroll
    for (int n = 0; n < 4; n++) {
        int col = bcol + wc * 64 + n * 16 + l15;
        float bval = bias[col];
#pragma unroll
        for (int m = 0; m < 4; m++) {
            int row0 = brow + wr * 64 + m * 16 + lg * 4;
            if (MODE == 3) {
#pragma unroll
                for (int r = 0; r < 4; r++)
                    outF[(size_t)(row0 + r) * DM + col] = acc[m][n][r] + bval;
            } else if (MODE == 0) {
                int h = col >> 6, d = col & 63;
#pragma unroll
                for (int r = 0; r < 4; r++) {
                    int row = row0 + r;
                    int b = row >> 10, q = row & 1023;
                    outB[((size_t)(b * H_ + h) * NQ + q) * 64 + d] = f2bf(acc[m][n][r] + bval);
                }
            } else if (MODE == 1) {
                int h = col >> 6, d = col & 63;
#pragma unroll
                for (int r = 0; r < 4; r++) {
                    int row = row0 + r;
                    int b = row >> 10, kk = row & 1023;
                    outB[((size_t)(b * H_ + h) * NKP + kk) * 64 + d] = f2bf(acc[m][n][r] + bval);
                }
            } else {  // MODE 2: Vt[bh][d][kk]
                int h = col >> 6, d = col & 63;
                int b = row0 >> 10, kk0 = row0 & 1023;
                short4v sv;
#pragma unroll
                for (int r = 0; r < 4; r++) sv[r] = f2bf(acc[m][n][r] + bval);
                *(short4v*)(outB + ((size_t)(b * H_ + h) * 64 + d) * NKP + kk0) = sv;
            }
        }
    }
}

// ---------------------------------------------------------------------------
// Kernel A: streaming exp. One wave = 16 q-rows x full 1088 kk strip.
// PF==0: store unnormalized P bf16 to workspace. PF==1: store fp32 into att.
// Also writes invv[bh][q] = 1/rowsum.
// ---------------------------------------------------------------------------
template <int PF>
__global__ __launch_bounds__(256) void exp_kernel(
    const short* __restrict__ Qh, const short* __restrict__ Kh,
    const unsigned char* __restrict__ mb, const int* __restrict__ mi,
    const int* __restrict__ flag,
    short* __restrict__ P, float* __restrict__ att, float* __restrict__ invv) {
    __shared__ float tbuf[4][16][36];   // [wave][q][kk+pad]; stride 36 dwords

    int swz = (blockIdx.x & 7) * 256 + (blockIdx.x >> 3);   // 16 blocks/bh per XCD
    int bh = swz >> 4;
    int wid = threadIdx.x >> 6;
    int qt = (swz & 15) * 4 + wid;
    int lane = threadIdx.x & 63;
    int l15 = lane & 15, lg = lane >> 4;
    int q0 = qt * 16;

    const short* Qb = Qh + ((size_t)bh * NQ + q0) * 64;
    const short* Kb = Kh + (size_t)bh * NKP * 64;
    const int is32 = *flag;

    bf16x8 aq0 = *(const bf16x8*)(Qb + (size_t)l15 * 64 + lg * 8);
    bf16x8 aq1 = *(const bf16x8*)(Qb + (size_t)l15 * 64 + 32 + lg * 8);

    float rs[4] = {0.f, 0.f, 0.f, 0.f};
    size_t mrow = (size_t)bh * NQ + q0 + lg * 4;            // + r
    short* Prow = P + ((size_t)bh * NQ + q0 + l15) * NKM;   // PF==0 store row
    float* arow = att + ((size_t)bh * NQ + q0 + l15) * NKM; // PF==1 store row

    for (int c = 0; c < 34; ++c) {
        int kk0 = c * 32;
#pragma unroll
        for (int tl = 0; tl < 2; ++tl) {
            int kt = kk0 + tl * 16;
            const short* Kr = Kb + (size_t)(kt + l15) * 64;
            bf16x8 k0 = *(const bf16x8*)(Kr + lg * 8);
            bf16x8 k1 = *(const bf16x8*)(Kr + 32 + lg * 8);
            f32x4 s = {0.f, 0.f, 0.f, 0.f};
            s = __builtin_amdgcn_mfma_f32_16x16x32_bf16(aq0, k0, s, 0, 0, 0);
            s = __builtin_amdgcn_mfma_f32_16x16x32_bf16(aq1, k1, s, 0, 0, 0);
            int kkt = kt + l15;
#pragma unroll
            for (int r = 0; r < 4; ++r) {
                float e = 0.f;
                if (kkt < NKM) {
                    bool dead = false;
                    if (kkt < NK) {
                        size_t midx = (mrow + r) * (size_t)NK + kkt;
                        dead = is32 ? (mi[midx] != 0) : (mb[midx] != 0);
                    }
                    e = dead ? 0.f : __expf(s[r] * 0.125f);
                }
                rs[r] += e;
                tbuf[wid][lg * 4 + r][tl * 16 + l15] = e;
            }
        }
        // per-wave LDS transpose read: row q_local=l15, kk chunk-local lg*8..
        float4 f0 = *(const float4*)(&tbuf[wid][l15][lg * 8]);
        float4 f1 = *(const float4*)(&tbuf[wid][l15][lg * 8 + 4]);
        int kks = kk0 + lg * 8;
        if (kks < NKM) {
            if (PF == 0) {
                bf16x8 pv;
                pv[0] = f2bf(f0.x); pv[1] = f2bf(f0.y); pv[2] = f2bf(f0.z); pv[3] = f2bf(f0.w);
                pv[4] = f2bf(f1.x); pv[5] = f2bf(f1.y); pv[6] = f2bf(f1.z); pv[7] = f2bf(f1.w);
                *(bf16x8*)(Prow + kks) = pv;
            } else {
                *(float4*)(arow + kks) = f0;
                *(float4*)(arow + kks + 4) = f1;
            }
        }
    }

#pragma unroll
    for (int r = 0; r < 4; ++r) {
#pragma unroll
        for (int o = 1; o < 16; o <<= 1) rs[r] += __shfl_xor(rs[r], o);
    }
    if (l15 == 0) {
#pragma unroll
        for (int r = 0; r < 4; ++r)
            invv[(size_t)bh * NQ + q0 + lg * 4 + r] = 1.f / rs[r];
    }
}

// ---------------------------------------------------------------------------
// Kernel B: att = P*inv (coalesced rows) + PV MFMA -> Ow = (P@V)*inv bf16.
// P rows ARE the MFMA A-fragment layout: no LDS bounce.
// ---------------------------------------------------------------------------
template <int PF>
__global__ __launch_bounds__(256) void pv_norm_kernel(
    const short* __restrict__ P, const short* __restrict__ Vt,
    const float* __restrict__ invv,
    float* __restrict__ att, short* __restrict__ Ow) {
    int swz = (blockIdx.x & 7) * 256 + (blockIdx.x >> 3);
    int bh = swz >> 4;
    int wid = threadIdx.x >> 6;
    int qt = (swz & 15) * 4 + wid;
    int lane = threadIdx.x & 63;
    int l15 = lane & 15, lg = lane >> 4;
    int q0 = qt * 16;

    const short* Vb = Vt + (size_t)bh * 64 * NKP;
    float invq = invv[(size_t)bh * NQ + q0 + l15];
    const short* Prow = P + ((size_t)bh * NQ + q0 + l15) * NKM;
    float* arow = att + ((size_t)bh * NQ + q0 + l15) * NKM;

    f32x4 po[4];
#pragma unroll
    for (int dt = 0; dt < 4; dt++) po[dt] = f32x4{0.f, 0.f, 0.f, 0.f};

    for (int c = 0; c < 34; ++c) {
        int kks = c * 32 + lg * 8;
        bf16x8 a;
        if (PF == 0) {
            a = *(const bf16x8*)(Prow + kks);   // padded; tail garbage * V==0
            if (kks < NKM) {
                float4 w0, w1;
                w0.x = bf2f(a[0]) * invq; w0.y = bf2f(a[1]) * invq;
                w0.z = bf2f(a[2]) * invq; w0.w = bf2f(a[3]) * invq;
                w1.x = bf2f(a[4]) * invq; w1.y = bf2f(a[5]) * invq;
                w1.z = bf2f(a[6]) * invq; w1.w = bf2f(a[7]) * invq;
                *(float4*)(arow + kks) = w0;
                *(float4*)(arow + kks + 4) = w1;
            }
        } else {
            if (kks < NKM) {
                float4 f0 = *(const float4*)(arow + kks);
                float4 f1 = *(const float4*)(arow + kks + 4);
                a[0] = f2bf(f0.x); a[1] = f2bf(f0.y); a[2] = f2bf(f0.z); a[3] = f2bf(f0.w);
                a[4] = f2bf(f1.x); a[5] = f2bf(f1.y); a[6] = f2bf(f1.z); a[7] = f2bf(f1.w);
                float4 w0, w1;
                w0.x = f0.x * invq; w0.y = f0.y * invq; w0.z = f0.z * invq; w0.w = f0.w * invq;
                w1.x = f1.x * invq; w1.y = f1.y * invq; w1.z = f1.z * invq; w1.w = f1.w * invq;
                *(float4*)(arow + kks) = w0;
                *(float4*)(arow + kks + 4) = w1;
            } else {
                a = bf16x8{0, 0, 0, 0, 0, 0, 0, 0};
            }
        }
#pragma unroll
        for (int dt = 0; dt < 4; dt++) {
            bf16x8 bv = *(const bf16x8*)(Vb + (size_t)(dt * 16 + l15) * NKP + c * 32 + lg * 8);
            po[dt] = __builtin_amdgcn_mfma_f32_16x16x32_bf16(a, bv, po[dt], 0, 0, 0);
        }
    }

    float invr[4];
#pragma unroll
    for (int r = 0; r < 4; ++r) invr[r] = invv[(size_t)bh * NQ + q0 + lg * 4 + r];
    int b = bh >> 4, h = bh & 15;
#pragma unroll
    for (int dt = 0; dt < 4; dt++)
#pragma unroll
        for (int r = 0; r < 4; ++r)
            Ow[((size_t)(b * NQ) + q0 + lg * 4 + r) * DM + h * 64 + dt * 16 + l15] =
                f2bf(po[dt][r] * invr[r]);
}

extern "C" void kernel_launch(void* const* d_in, const int* in_sizes, int n_in,
                              void* d_out, int out_size, void* d_ws, size_t ws_size,
                              hipStream_t stream) {
    const float* queries = (const float*)d_in[0];
    const float* keys    = (const float*)d_in[1];
    const float* values  = (const float*)d_in[2];
    const void*  mask    = d_in[3];
    const float* Wq = (const float*)d_in[4];
    const float* bq = (const float*)d_in[5];
    const float* Wk = (const float*)d_in[6];
    const float* bk = (const float*)d_in[7];
    const float* Wv = (const float*)d_in[8];
    const float* bv = (const float*)d_in[9];
    const float* Wo = (const float*)d_in[10];
    const float* bo = (const float*)d_in[11];
    const float* m_k = (const float*)d_in[12];
    const float* m_v = (const float*)d_in[13];

    // workspace layout
    short* WqT = (short*)d_ws;
    short* WkT = WqT + (size_t)DM * DM;
    short* WvT = WkT + (size_t)DM * DM;
    short* WoT = WvT + (size_t)DM * DM;
    short* Qh  = WoT + (size_t)DM * DM;                 // [128][1024][64]
    short* Kh  = Qh + (size_t)B_ * H_ * NQ * DK;        // [128][1104][64]
    short* Vt  = Kh + (size_t)B_ * H_ * NKP * DK;       // [128][64][1104]
    short* Ow  = Vt + (size_t)B_ * H_ * DK * NKP;       // [8192][1024]
    char*  after = (char*)(Ow + (size_t)B_ * NQ * DM);
    int*   flag = (int*)after;
    float* invv = (float*)(after + 64);                 // [128][1024]
    short* P    = (short*)(after + 64 + (size_t)B_ * H_ * NQ * 4);  // [128][1024][1064]
    size_t need = ((char*)P - (char*)d_ws) + (size_t)B_ * H_ * NQ * NKM * 2 + 64;
    const bool usep = (ws_size >= need);

    float* outO = (float*)d_out;                         // 8*1024*1024
    float* att  = outO + (size_t)B_ * NQ * DM;           // 8*16*1024*1064

    detect_mask_kernel<<<1, 256, 0, stream>>>((const unsigned int*)mask, 4096, flag);

    dim3 tg(32, 32);
    transpose_w_kernel<<<tg, 256, 0, stream>>>(Wq, WqT);
    transpose_w_kernel<<<tg, 256, 0, stream>>>(Wk, WkT);
    transpose_w_kernel<<<tg, 256, 0, stream>>>(Wv, WvT);
    transpose_w_kernel<<<tg, 256, 0, stream>>>(Wo, WoT);

    gemm_tile_kernel<0><<<512, 256, 0, stream>>>(queries, nullptr, WqT, bq, nullptr, Qh);
    gemm_tile_kernel<1><<<512, 256, 0, stream>>>(keys,    nullptr, WkT, bk, nullptr, Kh);
    gemm_tile_kernel<2><<<512, 256, 0, stream>>>(values,  nullptr, WvT, bv, nullptr, Vt);

    fill_mem_kernel<<<2560, 256, 0, stream>>>(m_k, m_v, Kh, Vt);

    if (usep) {
        exp_kernel<0><<<2048, 256, 0, stream>>>(Qh, Kh, (const unsigned char*)mask,
                                                (const int*)mask, flag, P, att, invv);
        pv_norm_kernel<0><<<2048, 256, 0, stream>>>(P, Vt, invv, att, Ow);
    } else {
        exp_kernel<1><<<2048, 256, 0, stream>>>(Qh, Kh, (const unsigned char*)mask,
                                                (const int*)mask, flag, nullptr, att, invv);
        pv_norm_kernel<1><<<2048, 256, 0, stream>>>(nullptr, Vt, invv, att, Ow);
    }

    gemm_tile_kernel<3><<<512, 256, 0, stream>>>(nullptr, Ow, WoT, bo, outO, Qh /*unused*/);
}

// Round 4
// 986.123 us; speedup vs baseline: 1.1412x; 1.1412x over previous
//
#include <hip/hip_runtime.h>
#include <hip/hip_bf16.h>

// ---------------------------------------------------------------------------
// ScaledDotProductAttentionMemory, round 3:
//  - exp_kernel rewritten with SWAPPED QK^T operands: per-lane C fragment is
//    4 consecutive kk of one q row -> u32 mask loads, direct 8B P stores,
//    NO LDS round-trip (the round-2 serialization point), 32 q per wave.
//  - pv_norm_kernel widened to 32 q per wave (V frags shared across q-tiles).
// Outputs: out (8,1024,1024) fp32 ; att (8,16,1024,1064) fp32
// ---------------------------------------------------------------------------

#define B_ 8
#define NQ 1024
#define NK 1024
#define DM 1024
#define H_ 16
#define DK 64
#define NKM 1064   // nk + M
#define NKP 1104   // padded row length for Kh/Vt

typedef __attribute__((ext_vector_type(8))) short bf16x8;
typedef __attribute__((ext_vector_type(4))) float f32x4;
typedef __attribute__((ext_vector_type(4))) short short4v;

static __device__ __forceinline__ short f2bf(float x) {
    __hip_bfloat16 h = __float2bfloat16(x);
    return __builtin_bit_cast(short, h);
}
static __device__ __forceinline__ float bf2f(short s) {
    unsigned int u = ((unsigned int)(unsigned short)s) << 16;
    return __builtin_bit_cast(float, u);
}

static __device__ __forceinline__ bf16x8 pack8(const float* __restrict__ p) {
    float4 f0 = *(const float4*)p;
    float4 f1 = *(const float4*)(p + 4);
    bf16x8 a;
    a[0] = f2bf(f0.x); a[1] = f2bf(f0.y); a[2] = f2bf(f0.z); a[3] = f2bf(f0.w);
    a[4] = f2bf(f1.x); a[5] = f2bf(f1.y); a[6] = f2bf(f1.z); a[7] = f2bf(f1.w);
    return a;
}

// --- mask dtype probe: bool(1B) vs int32(4B) -------------------------------
__global__ void detect_mask_kernel(const unsigned int* __restrict__ m, int n_dwords,
                                   int* __restrict__ flag) {
    __shared__ int any_big;
    if (threadIdx.x == 0) any_big = 0;
    __syncthreads();
    for (int i = threadIdx.x; i < n_dwords; i += blockDim.x)
        if (m[i] > 1u) any_big = 1;
    __syncthreads();
    if (threadIdx.x == 0) *flag = any_big ? 0 : 1;   // 1 => int32, 0 => bytes
}

// --- W (K x N) fp32 -> WT (N x K) bf16 --------------------------------------
__global__ void transpose_w_kernel(const float* __restrict__ W, short* __restrict__ WT) {
    __shared__ float t[32][33];
    int tx = threadIdx.x & 31, ty = threadIdx.x >> 5;
    int k0 = blockIdx.x * 32, n0 = blockIdx.y * 32;
#pragma unroll
    for (int r = 0; r < 4; r++)
        t[ty + 8 * r][tx] = W[(size_t)(k0 + ty + 8 * r) * DM + n0 + tx];
    __syncthreads();
#pragma unroll
    for (int r = 0; r < 4; r++)
        WT[(size_t)(n0 + ty + 8 * r) * DM + k0 + tx] = f2bf(t[tx][ty + 8 * r]);
}

// --- memory-slot rows of Kh / Vt (rows 1024..1103; zeros past 1063) --------
__global__ void fill_mem_kernel(const float* __restrict__ m_k, const float* __restrict__ m_v,
                                short* __restrict__ Kh, short* __restrict__ Vt) {
    int blk = blockIdx.x;           // 128 bh * 20 row-groups
    int bh = blk / 20, rb = blk % 20;
    int r = rb * 4 + (threadIdx.x >> 6);    // 0..79
    int d = threadIdx.x & 63;
    int h = bh & 15;
    float kv = 0.f, vv = 0.f;
    if (r < 40) {
        kv = 8.0f * m_k[(size_t)(r * H_ + h) * DK + d];               // sqrt(DK)=8
        vv = 6.324555320336759f * m_v[(size_t)(r * H_ + h) * DK + d]; // sqrt(M)
    }
    int kk = 1024 + r;
    Kh[((size_t)bh * NKP + kk) * 64 + d] = f2bf(kv);
    Vt[((size_t)bh * 64 + d) * NKP + kk] = f2bf(vv);
}

// ---------------------------------------------------------------------------
// Tiled GEMM (unchanged): C[8192x1024] = A @ BT^T + bias.
// ---------------------------------------------------------------------------
template <int MODE>
__global__ __launch_bounds__(256) void gemm_tile_kernel(
    const float* __restrict__ Af, const short* __restrict__ Ab,
    const short* __restrict__ BT, const float* __restrict__ bias,
    float* __restrict__ outF, short* __restrict__ outB) {
    __shared__ short As[2][4096];
    __shared__ short Bs[2][4096];

    const int tid = threadIdx.x;
    const int lane = tid & 63;
    const int wid = tid >> 6;
    int swz = (blockIdx.x & 7) * 64 + (blockIdx.x >> 3);
    const int mt = swz >> 3;
    const int nt = swz & 7;
    const int brow = mt * 128, bcol = nt * 128;
    const int wr = wid >> 1, wc = wid & 1;
    const int l15 = lane & 15, lg = lane >> 4;

    f32x4 acc[4][4];
#pragma unroll
    for (int m = 0; m < 4; m++)
#pragma unroll
        for (int n = 0; n < 4; n++) acc[m][n] = f32x4{0.f, 0.f, 0.f, 0.f};

    auto stage = [&](int buf, int k0) {
#pragma unroll
        for (int i = 0; i < 2; i++) {
            int c = tid + i * 256;
            int row = c >> 2, slot = c & 3;
            int sw = slot ^ (row & 3);
            bf16x8 av;
            if (MODE == 3) {
                av = *(const bf16x8*)(Ab + (size_t)(brow + row) * DM + k0 + slot * 8);
            } else {
                av = pack8(Af + (size_t)(brow + row) * DM + k0 + slot * 8);
            }
            *(bf16x8*)(&As[buf][row * 32 + sw * 8]) = av;
            bf16x8 bv = *(const bf16x8*)(BT + (size_t)(bcol + row) * DM + k0 + slot * 8);
            *(bf16x8*)(&Bs[buf][row * 32 + sw * 8]) = bv;
        }
    };

    stage(0, 0);
    for (int kt = 0; kt < 32; ++kt) {
        __syncthreads();
        if (kt + 1 < 32) stage((kt + 1) & 1, (kt + 1) * 32);
        const short* Ab_ = As[kt & 1];
        const short* Bb_ = Bs[kt & 1];
        bf16x8 a[4], b[4];
#pragma unroll
        for (int m = 0; m < 4; m++) {
            int row = wr * 64 + m * 16 + l15;
            a[m] = *(const bf16x8*)(Ab_ + row * 32 + ((lg ^ (row & 3)) * 8));
        }
#pragma unroll
        for (int n = 0; n < 4; n++) {
            int row = wc * 64 + n * 16 + l15;
            b[n] = *(const bf16x8*)(Bb_ + row * 32 + ((lg ^ (row & 3)) * 8));
        }
#pragma unroll
        for (int m = 0; m < 4; m++)
#pragma unroll
            for (int n = 0; n < 4; n++)
                acc[m][n] = __builtin_amdgcn_mfma_f32_16x16x32_bf16(a[m], b[n], acc[m][n], 0, 0, 0);
    }

#pragma unroll
    for (int n = 0; n < 4; n++) {
        int col = bcol + wc * 64 + n * 16 + l15;
        float bval = bias[col];
#pragma unroll
        for (int m = 0; m < 4; m++) {
            int row0 = brow + wr * 64 + m * 16 + lg * 4;
            if (MODE == 3) {
#pragma unroll
                for (int r = 0; r < 4; r++)
                    outF[(size_t)(row0 + r) * DM + col] = acc[m][n][r] + bval;
            } else if (MODE == 0) {
                int h = col >> 6, d = col & 63;
#pragma unroll
                for (int r = 0; r < 4; r++) {
                    int row = row0 + r;
                    int b = row >> 10, q = row & 1023;
                    outB[((size_t)(b * H_ + h) * NQ + q) * 64 + d] = f2bf(acc[m][n][r] + bval);
                }
            } else if (MODE == 1) {
                int h = col >> 6, d = col & 63;
#pragma unroll
                for (int r = 0; r < 4; r++) {
                    int row = row0 + r;
                    int b = row >> 10, kk = row & 1023;
                    outB[((size_t)(b * H_ + h) * NKP + kk) * 64 + d] = f2bf(acc[m][n][r] + bval);
                }
            } else {  // MODE 2: Vt[bh][d][kk]
                int h = col >> 6, d = col & 63;
                int b = row0 >> 10, kk0 = row0 & 1023;
                short4v sv;
#pragma unroll
                for (int r = 0; r < 4; r++) sv[r] = f2bf(acc[m][n][r] + bval);
                *(short4v*)(outB + ((size_t)(b * H_ + h) * 64 + d) * NKP + kk0) = sv;
            }
        }
    }
}

// ---------------------------------------------------------------------------
// Pass 1: swapped-operand QK^T -> exp -> P (unnormalized) + rowsum inv.
// One wave = 32 q rows (2 q-tiles) x full 1088 kk strip. No LDS.
// Per-lane fragment: q = lane&15 (+16*t), kk = base + (lane>>4)*4 + r.
// PF==0: P bf16 to workspace.  PF==1: fp32 into att (fallback).
// ---------------------------------------------------------------------------
template <int PF>
__global__ __launch_bounds__(256) void exp_kernel(
    const short* __restrict__ Qh, const short* __restrict__ Kh,
    const unsigned char* __restrict__ mb, const int* __restrict__ mi,
    const int* __restrict__ flag,
    short* __restrict__ P, float* __restrict__ attF, float* __restrict__ invv) {
    int swz = (blockIdx.x & 7) * 128 + (blockIdx.x >> 3);   // 1024 blocks
    int bh = swz >> 3;                                      // 8 blocks per bh
    int wid = threadIdx.x >> 6;
    int q0 = (swz & 7) * 128 + wid * 32;
    int lane = threadIdx.x & 63;
    int l15 = lane & 15, lg = lane >> 4;

    const short* Qb = Qh + (size_t)bh * NQ * 64;
    const short* Kb = Kh + (size_t)bh * NKP * 64;
    const int is32 = *flag;

    // Q B-fragments: 2 q-tiles x 2 k-halves (lane&15 = q row)
    bf16x8 aq[2][2];
#pragma unroll
    for (int t = 0; t < 2; t++)
#pragma unroll
        for (int hh = 0; hh < 2; hh++)
            aq[t][hh] = *(const bf16x8*)(Qb + (size_t)(q0 + t * 16 + l15) * 64 + hh * 32 + lg * 8);

    float rs[2] = {0.f, 0.f};
    size_t qrow[2];
    qrow[0] = (size_t)bh * NQ + q0 + l15;
    qrow[1] = qrow[0] + 16;

    for (int c = 0; c < 34; ++c) {
        int ntl = (c == 33) ? 1 : 2;      // kk >= 1072 entirely dead
        for (int tl = 0; tl < ntl; ++tl) {
            int kt = c * 32 + tl * 16;
            const short* Kr = Kb + (size_t)(kt + l15) * 64;
            bf16x8 k0 = *(const bf16x8*)(Kr + lg * 8);
            bf16x8 k1 = *(const bf16x8*)(Kr + 32 + lg * 8);
            int kkbase = kt + lg * 4;      // this lane's 4 consecutive kk
#pragma unroll
            for (int t = 0; t < 2; t++) {
                f32x4 s = {0.f, 0.f, 0.f, 0.f};
                s = __builtin_amdgcn_mfma_f32_16x16x32_bf16(k0, aq[t][0], s, 0, 0, 0);
                s = __builtin_amdgcn_mfma_f32_16x16x32_bf16(k1, aq[t][1], s, 0, 0, 0);
                unsigned mu = 0;
                if (kkbase < NK) {
                    if (is32) {
                        int4 mv = *(const int4*)(mi + qrow[t] * NK + kkbase);
                        mu = (mv.x ? 1u : 0u) | (mv.y ? 0x100u : 0u) |
                             (mv.z ? 0x10000u : 0u) | (mv.w ? 0x1000000u : 0u);
                    } else {
                        mu = *(const unsigned*)(mb + qrow[t] * NK + kkbase);
                    }
                }
                float e[4];
#pragma unroll
                for (int r = 0; r < 4; r++) {
                    bool dead = (kkbase + r >= NKM) || (((mu >> (8 * r)) & 0xffu) != 0u);
                    float ev = __expf(s[r] * 0.125f);
                    e[r] = dead ? 0.f : ev;
                    rs[t] += e[r];
                }
                if (kkbase < NKM) {
                    if (PF == 0) {
                        short4v pv;
                        pv[0] = f2bf(e[0]); pv[1] = f2bf(e[1]);
                        pv[2] = f2bf(e[2]); pv[3] = f2bf(e[3]);
                        *(short4v*)(P + qrow[t] * NKM + kkbase) = pv;
                    } else {
                        float4 fv = {e[0], e[1], e[2], e[3]};
                        *(float4*)(attF + qrow[t] * NKM + kkbase) = fv;
                    }
                }
            }
        }
    }
    // reduce rowsums across the 4 lane-groups (same l15 = same q)
#pragma unroll
    for (int t = 0; t < 2; t++) {
        rs[t] += __shfl_xor(rs[t], 16);
        rs[t] += __shfl_xor(rs[t], 32);
    }
    if (lg == 0) {
        invv[qrow[0]] = 1.f / rs[0];
        invv[qrow[1]] = 1.f / rs[1];
    }
}

// ---------------------------------------------------------------------------
// Pass 2: att = P*inv (coalesced float4 rows) + PV MFMA -> Ow = (P@V)*inv.
// One wave = 32 q (2 q-tiles); V fragments shared across q-tiles. No LDS.
// ---------------------------------------------------------------------------
template <int PF>
__global__ __launch_bounds__(256) void pv_norm_kernel(
    const short* __restrict__ P, const short* __restrict__ Vt,
    const float* __restrict__ invv,
    float* __restrict__ att, short* __restrict__ Ow) {
    int swz = (blockIdx.x & 7) * 128 + (blockIdx.x >> 3);
    int bh = swz >> 3;
    int wid = threadIdx.x >> 6;
    int q0 = (swz & 7) * 128 + wid * 32;
    int lane = threadIdx.x & 63;
    int l15 = lane & 15, lg = lane >> 4;

    const short* Vb = Vt + (size_t)bh * 64 * NKP;
    size_t qrow[2];
    qrow[0] = (size_t)bh * NQ + q0 + l15;
    qrow[1] = qrow[0] + 16;
    float invq[2] = {invv[qrow[0]], invv[qrow[1]]};

    f32x4 po[2][4];
#pragma unroll
    for (int t = 0; t < 2; t++)
#pragma unroll
        for (int dt = 0; dt < 4; dt++) po[t][dt] = f32x4{0.f, 0.f, 0.f, 0.f};

    for (int c = 0; c < 34; ++c) {
        int kks = c * 32 + lg * 8;
        bf16x8 bv[4];
#pragma unroll
        for (int dt = 0; dt < 4; dt++)
            bv[dt] = *(const bf16x8*)(Vb + (size_t)(dt * 16 + l15) * NKP + kks);
#pragma unroll
        for (int t = 0; t < 2; t++) {
            bf16x8 a;
            if (PF == 0) {
                a = *(const bf16x8*)(P + qrow[t] * NKM + kks);  // tail overread * V==0
                if (kks < NKM) {
                    float4 w0, w1;
                    w0.x = bf2f(a[0]) * invq[t]; w0.y = bf2f(a[1]) * invq[t];
                    w0.z = bf2f(a[2]) * invq[t]; w0.w = bf2f(a[3]) * invq[t];
                    w1.x = bf2f(a[4]) * invq[t]; w1.y = bf2f(a[5]) * invq[t];
                    w1.z = bf2f(a[6]) * invq[t]; w1.w = bf2f(a[7]) * invq[t];
                    *(float4*)(att + qrow[t] * NKM + kks) = w0;
                    *(float4*)(att + qrow[t] * NKM + kks + 4) = w1;
                }
            } else {
                if (kks < NKM) {
                    float4 f0 = *(const float4*)(att + qrow[t] * NKM + kks);
                    float4 f1 = *(const float4*)(att + qrow[t] * NKM + kks + 4);
                    a[0] = f2bf(f0.x); a[1] = f2bf(f0.y); a[2] = f2bf(f0.z); a[3] = f2bf(f0.w);
                    a[4] = f2bf(f1.x); a[5] = f2bf(f1.y); a[6] = f2bf(f1.z); a[7] = f2bf(f1.w);
                    float4 w0, w1;
                    w0.x = f0.x * invq[t]; w0.y = f0.y * invq[t];
                    w0.z = f0.z * invq[t]; w0.w = f0.w * invq[t];
                    w1.x = f1.x * invq[t]; w1.y = f1.y * invq[t];
                    w1.z = f1.z * invq[t]; w1.w = f1.w * invq[t];
                    *(float4*)(att + qrow[t] * NKM + kks) = w0;
                    *(float4*)(att + qrow[t] * NKM + kks + 4) = w1;
                } else {
                    a = bf16x8{0, 0, 0, 0, 0, 0, 0, 0};
                }
            }
#pragma unroll
            for (int dt = 0; dt < 4; dt++)
                po[t][dt] = __builtin_amdgcn_mfma_f32_16x16x32_bf16(a, bv[dt], po[t][dt], 0, 0, 0);
        }
    }

    int b = bh >> 4, h = bh & 15;
#pragma unroll
    for (int t = 0; t < 2; t++) {
        float invr[4];
#pragma unroll
        for (int r = 0; r < 4; r++)
            invr[r] = invv[(size_t)bh * NQ + q0 + t * 16 + lg * 4 + r];
#pragma unroll
        for (int dt = 0; dt < 4; dt++)
#pragma unroll
            for (int r = 0; r < 4; r++)
                Ow[((size_t)b * NQ + q0 + t * 16 + lg * 4 + r) * DM + h * 64 + dt * 16 + l15] =
                    f2bf(po[t][dt][r] * invr[r]);
    }
}

extern "C" void kernel_launch(void* const* d_in, const int* in_sizes, int n_in,
                              void* d_out, int out_size, void* d_ws, size_t ws_size,
                              hipStream_t stream) {
    const float* queries = (const float*)d_in[0];
    const float* keys    = (const float*)d_in[1];
    const float* values  = (const float*)d_in[2];
    const void*  mask    = d_in[3];
    const float* Wq = (const float*)d_in[4];
    const float* bq = (const float*)d_in[5];
    const float* Wk = (const float*)d_in[6];
    const float* bk = (const float*)d_in[7];
    const float* Wv = (const float*)d_in[8];
    const float* bv = (const float*)d_in[9];
    const float* Wo = (const float*)d_in[10];
    const float* bo = (const float*)d_in[11];
    const float* m_k = (const float*)d_in[12];
    const float* m_v = (const float*)d_in[13];

    // workspace layout
    short* WqT = (short*)d_ws;
    short* WkT = WqT + (size_t)DM * DM;
    short* WvT = WkT + (size_t)DM * DM;
    short* WoT = WvT + (size_t)DM * DM;
    short* Qh  = WoT + (size_t)DM * DM;                 // [128][1024][64]
    short* Kh  = Qh + (size_t)B_ * H_ * NQ * DK;        // [128][1104][64]
    short* Vt  = Kh + (size_t)B_ * H_ * NKP * DK;       // [128][64][1104]
    short* Ow  = Vt + (size_t)B_ * H_ * DK * NKP;       // [8192][1024]
    char*  after = (char*)(Ow + (size_t)B_ * NQ * DM);
    int*   flag = (int*)after;
    float* invv = (float*)(after + 64);                 // [128][1024]
    short* P    = (short*)(after + 64 + (size_t)B_ * H_ * NQ * 4);  // [128][1024][1064]
    size_t need = ((char*)P - (char*)d_ws) + ((size_t)B_ * H_ * NQ * NKM + 128) * 2;
    const bool usep = (ws_size >= need);

    float* outO = (float*)d_out;                         // 8*1024*1024
    float* att  = outO + (size_t)B_ * NQ * DM;           // 8*16*1024*1064

    detect_mask_kernel<<<1, 256, 0, stream>>>((const unsigned int*)mask, 4096, flag);

    dim3 tg(32, 32);
    transpose_w_kernel<<<tg, 256, 0, stream>>>(Wq, WqT);
    transpose_w_kernel<<<tg, 256, 0, stream>>>(Wk, WkT);
    transpose_w_kernel<<<tg, 256, 0, stream>>>(Wv, WvT);
    transpose_w_kernel<<<tg, 256, 0, stream>>>(Wo, WoT);

    gemm_tile_kernel<0><<<512, 256, 0, stream>>>(queries, nullptr, WqT, bq, nullptr, Qh);
    gemm_tile_kernel<1><<<512, 256, 0, stream>>>(keys,    nullptr, WkT, bk, nullptr, Kh);
    gemm_tile_kernel<2><<<512, 256, 0, stream>>>(values,  nullptr, WvT, bv, nullptr, Vt);

    fill_mem_kernel<<<2560, 256, 0, stream>>>(m_k, m_v, Kh, Vt);

    if (usep) {
        exp_kernel<0><<<1024, 256, 0, stream>>>(Qh, Kh, (const unsigned char*)mask,
                                                (const int*)mask, flag, P, att, invv);
        pv_norm_kernel<0><<<1024, 256, 0, stream>>>(P, Vt, invv, att, Ow);
    } else {
        exp_kernel<1><<<1024, 256, 0, stream>>>(Qh, Kh, (const unsigned char*)mask,
                                                (const int*)mask, flag, nullptr, att, invv);
        pv_norm_kernel<1><<<1024, 256, 0, stream>>>(nullptr, Vt, invv, att, Ow);
    }

    gemm_tile_kernel<3><<<512, 256, 0, stream>>>(nullptr, Ow, WoT, bo, outO, Qh /*unused*/);
}